// Round 1
// baseline (7235.714 us; speedup 1.0000x reference)
//
#include <hip/hip_runtime.h>
#include <cstdint>

// binary_disordered_RNNwavefunction: 128-step 2-layer GRU + MLP + softmax +
// threefry categorical sampling, B=8192, H=128, I=2.
//
// Key structural fact: batch rows are fully independent (weights shared,
// softmax over I=2 within a row, sampling per row). Each block owns BT=16
// batch rows for all 128 steps -> single kernel launch, no grid sync.
//
// RNG: modern JAX (jax_threefry_partitionable=True) semantics:
//   sample_keys[n] = threefry2x32((0,42), (0, n))            [fold-like split]
//   bits(b,i)      = o0 ^ o1 of threefry2x32(key_n, (0, 2b+i))
//   u = max(tiny, (bitcast((bits>>9)|0x3F800000)-1) * (1-tiny) + tiny)
//   gumbel = -log(-log(u)); sample = argmax(log(p) + gumbel)  (tie -> idx 0)
// FALLBACKS if absmax ~O(1) next round: (a) bits = o0 only; (b) legacy
// non-partitionable split/random_bits counter scheme.

namespace {

constexpr int NSTEPS = 128;
constexpr int HDIM = 128;
constexpr int G3H = 384;
constexpr int BT = 16;        // batch rows per block
constexpr int THREADS = 256;
constexpr int HP = 132;       // padded LDS row stride for h (bank spread, 16B aligned)
constexpr int SP = 516;       // padded LDS row stride for scratch

__device__ __forceinline__ float dot4(const float4 a, const float4 b, float c) {
  c = fmaf(a.x, b.x, c);
  c = fmaf(a.y, b.y, c);
  c = fmaf(a.z, b.z, c);
  c = fmaf(a.w, b.w, c);
  return c;
}

__device__ __forceinline__ void tf2x32(uint32_t k0, uint32_t k1,
                                       uint32_t x0, uint32_t x1,
                                       uint32_t& o0, uint32_t& o1) {
  const uint32_t ks2 = k0 ^ k1 ^ 0x1BD11BDAu;
  uint32_t v0 = x0 + k0;
  uint32_t v1 = x1 + k1;
  const uint32_t ks[3] = {k0, k1, ks2};
  const uint32_t rotA[4] = {13u, 15u, 26u, 6u};
  const uint32_t rotB[4] = {17u, 29u, 16u, 24u};
#pragma unroll
  for (int i = 0; i < 5; ++i) {
#pragma unroll
    for (int j = 0; j < 4; ++j) {
      const uint32_t r = (i & 1) ? rotB[j] : rotA[j];
      v0 += v1;
      v1 = (v1 << r) | (v1 >> (32u - r));
      v1 ^= v0;
    }
    v0 += ks[(i + 1) % 3];
    v1 += ks[(i + 2) % 3] + (uint32_t)(i + 1);
  }
  o0 = v0;
  o1 = v1;
}

__device__ __forceinline__ float u01_from_bits(uint32_t bits) {
  const float tiny = 1.1754943508222875e-38f;  // np.finfo(f32).tiny
  float f = __uint_as_float((bits >> 9) | 0x3F800000u) - 1.0f;
  float u = f * (1.0f - tiny) + tiny;
  return fmaxf(tiny, u);
}

__device__ __forceinline__ float sigmoidf(float x) {
  return 1.0f / (1.0f + expf(-x));
}

}  // namespace

extern "C" __global__ __launch_bounds__(256, 2)
void rnn_wavefn_kernel(const float* __restrict__ inputs,
                       const float* __restrict__ Wih0,
                       const float* __restrict__ Whh0,
                       const float* __restrict__ bih0,
                       const float* __restrict__ bhh0,
                       const float* __restrict__ Wih1,
                       const float* __restrict__ Whh1,
                       const float* __restrict__ bih1,
                       const float* __restrict__ bhh1,
                       const float* __restrict__ W1,
                       const float* __restrict__ b1,
                       const float* __restrict__ W2,
                       const float* __restrict__ b2,
                       float* __restrict__ out) {
  __shared__ float h1[BT][HP];
  __shared__ float h2[BT][HP];
  __shared__ float S[BT][SP];   // [0,384): gate scratch, [384,512): gi_n / hdn
  __shared__ float xin[BT][2];

  const int tid = threadIdx.x;
  const int b0 = blockIdx.x * BT;

  // GEMM-phase mapping: 64 j-threads x 4 b-threads; 6 rows x 4 batch each.
  const int tj = tid >> 2;        // 0..63
  const int tb = (tid & 3) * 4;   // {0,4,8,12}

  for (int i = tid; i < BT * HP; i += THREADS) {
    ((float*)h1)[i] = 0.0f;
    ((float*)h2)[i] = 0.0f;
  }
  if (tid < BT * 2) {
    xin[tid >> 1][tid & 1] = inputs[(b0 + (tid >> 1)) * 2 + (tid & 1)];
  }
  __syncthreads();

  for (int n = 0; n < NSTEPS; ++n) {
    const float* __restrict__ Wih0n = Wih0 + (size_t)n * G3H * 2;
    const float* __restrict__ Whh0n = Whh0 + (size_t)n * G3H * HDIM;
    const float* __restrict__ bih0n = bih0 + (size_t)n * G3H;
    const float* __restrict__ bhh0n = bhh0 + (size_t)n * G3H;
    const float* __restrict__ Wih1n = Wih1 + (size_t)n * G3H * HDIM;
    const float* __restrict__ Whh1n = Whh1 + (size_t)n * G3H * HDIM;
    const float* __restrict__ bih1n = bih1 + (size_t)n * G3H;
    const float* __restrict__ bhh1n = bhh1 + (size_t)n * G3H;
    const float* __restrict__ W1n = W1 + (size_t)n * HDIM * HDIM;
    const float* __restrict__ b1n = b1 + (size_t)n * HDIM;
    const float* __restrict__ W2n = W2 + (size_t)n * 2 * HDIM;
    const float* __restrict__ b2n = b2 + (size_t)n * 2;

    // ---------- GH0: S[b][j] = bhh0[j] + Whh0[j,:] . h1[b,:]
    {
      float acc[6][4];
#pragma unroll
      for (int g = 0; g < 6; ++g) {
        const float bias = bhh0n[tj + g * 64];
#pragma unroll
        for (int i = 0; i < 4; ++i) acc[g][i] = bias;
      }
      for (int kk = 0; kk < HDIM; kk += 16) {  // 16-float chunks: full 64B W-line reuse
#pragma unroll
        for (int s = 0; s < 4; ++s) {
          const int k = kk + s * 4;
          float4 w[6];
#pragma unroll
          for (int g = 0; g < 6; ++g)
            w[g] = *(const float4*)(Whh0n + (size_t)(tj + g * 64) * HDIM + k);
#pragma unroll
          for (int i = 0; i < 4; ++i) {
            const float4 hv = *(const float4*)&h1[tb + i][k];
#pragma unroll
            for (int g = 0; g < 6; ++g) acc[g][i] = dot4(w[g], hv, acc[g][i]);
          }
        }
      }
#pragma unroll
      for (int g = 0; g < 6; ++g)
#pragma unroll
        for (int i = 0; i < 4; ++i) S[tb + i][tj + g * 64] = acc[g][i];
    }
    __syncthreads();

    // ---------- C0: GRU0 combine -> h1   (gi from 2-wide x recomputed inline)
#pragma unroll
    for (int rep = 0; rep < 8; ++rep) {
      const int idx = tid + rep * THREADS;
      const int b = idx >> 7;
      const int d = idx & 127;
      const float x0 = xin[b][0];
      const float x1 = xin[b][1];
      const float gir = fmaf(Wih0n[d * 2 + 0], x0, fmaf(Wih0n[d * 2 + 1], x1, bih0n[d]));
      const float giz = fmaf(Wih0n[(d + 128) * 2 + 0], x0,
                             fmaf(Wih0n[(d + 128) * 2 + 1], x1, bih0n[d + 128]));
      const float gin = fmaf(Wih0n[(d + 256) * 2 + 0], x0,
                             fmaf(Wih0n[(d + 256) * 2 + 1], x1, bih0n[d + 256]));
      const float r = sigmoidf(gir + S[b][d]);
      const float z = sigmoidf(giz + S[b][d + 128]);
      const float nn = tanhf(gin + r * S[b][d + 256]);
      h1[b][d] = (1.0f - z) * nn + z * h1[b][d];
    }
    __syncthreads();

    // ---------- GH1a: S[b][j] = bhh1[j] + Whh1[j,:] . h2[b,:]
    {
      float acc[6][4];
#pragma unroll
      for (int g = 0; g < 6; ++g) {
        const float bias = bhh1n[tj + g * 64];
#pragma unroll
        for (int i = 0; i < 4; ++i) acc[g][i] = bias;
      }
      for (int kk = 0; kk < HDIM; kk += 16) {
#pragma unroll
        for (int s = 0; s < 4; ++s) {
          const int k = kk + s * 4;
          float4 w[6];
#pragma unroll
          for (int g = 0; g < 6; ++g)
            w[g] = *(const float4*)(Whh1n + (size_t)(tj + g * 64) * HDIM + k);
#pragma unroll
          for (int i = 0; i < 4; ++i) {
            const float4 hv = *(const float4*)&h2[tb + i][k];
#pragma unroll
            for (int g = 0; g < 6; ++g) acc[g][i] = dot4(w[g], hv, acc[g][i]);
          }
        }
      }
#pragma unroll
      for (int g = 0; g < 6; ++g)
#pragma unroll
        for (int i = 0; i < 4; ++i) S[tb + i][tj + g * 64] = acc[g][i];
    }
    // no barrier: GH1b touches exactly the same (thread -> S slot) ownership

    // ---------- GH1b: gi1 = bih1 + Wih1 . h1new; r,z summed into S, n kept
    // separate at S[b][row+128] (rows 256..383 -> slots 384..511).
    {
      float acc[6][4];
#pragma unroll
      for (int g = 0; g < 6; ++g) {
        const float bias = bih1n[tj + g * 64];
#pragma unroll
        for (int i = 0; i < 4; ++i) acc[g][i] = bias;
      }
      for (int kk = 0; kk < HDIM; kk += 16) {
#pragma unroll
        for (int s = 0; s < 4; ++s) {
          const int k = kk + s * 4;
          float4 w[6];
#pragma unroll
          for (int g = 0; g < 6; ++g)
            w[g] = *(const float4*)(Wih1n + (size_t)(tj + g * 64) * HDIM + k);
#pragma unroll
          for (int i = 0; i < 4; ++i) {
            const float4 hv = *(const float4*)&h1[tb + i][k];
#pragma unroll
            for (int g = 0; g < 6; ++g) acc[g][i] = dot4(w[g], hv, acc[g][i]);
          }
        }
      }
#pragma unroll
      for (int g = 0; g < 6; ++g) {
        const int row = tj + g * 64;
#pragma unroll
        for (int i = 0; i < 4; ++i) {
          if (row < 256) S[tb + i][row] += acc[g][i];      // r,z: gi+gh summed
          else           S[tb + i][row + 128] = acc[g][i]; // n: gi kept separate
        }
      }
    }
    __syncthreads();

    // ---------- C1: GRU1 combine -> h2, then s = cos(h2)+1e-10 into S[b][0..128)
#pragma unroll
    for (int rep = 0; rep < 8; ++rep) {
      const int idx = tid + rep * THREADS;
      const int b = idx >> 7;
      const int d = idx & 127;
      const float r = sigmoidf(S[b][d]);
      const float z = sigmoidf(S[b][d + 128]);
      const float nn = tanhf(S[b][d + 384] + r * S[b][d + 256]);
      const float h2n = (1.0f - z) * nn + z * h2[b][d];
      h2[b][d] = h2n;
      S[b][d] = cosf(h2n) + 1e-10f;  // only owner thread reads/writes this slot
    }
    __syncthreads();

    // ---------- HDN: S[b][384+d] = relu(b1[d] + W1[d,:] . s[b,:])
    {
      float acc[2][4];
#pragma unroll
      for (int g = 0; g < 2; ++g) {
        const float bias = b1n[tj + g * 64];
#pragma unroll
        for (int i = 0; i < 4; ++i) acc[g][i] = bias;
      }
      for (int kk = 0; kk < HDIM; kk += 16) {
#pragma unroll
        for (int s = 0; s < 4; ++s) {
          const int k = kk + s * 4;
          float4 w[2];
          w[0] = *(const float4*)(W1n + (size_t)(tj)*HDIM + k);
          w[1] = *(const float4*)(W1n + (size_t)(tj + 64) * HDIM + k);
#pragma unroll
          for (int i = 0; i < 4; ++i) {
            const float4 sv = *(const float4*)&S[tb + i][k];
            acc[0][i] = dot4(w[0], sv, acc[0][i]);
            acc[1][i] = dot4(w[1], sv, acc[1][i]);
          }
        }
      }
#pragma unroll
      for (int g = 0; g < 2; ++g)
#pragma unroll
        for (int i = 0; i < 4; ++i)
          S[tb + i][384 + tj + g * 64] = fmaxf(acc[g][i], 0.0f);
    }
    __syncthreads();

    // ---------- OUT: logits, softmax+1e-10, store p, threefry-gumbel sample
    {
      const int lane = tid & 15;
      const int b = tid >> 4;
      const int kb = lane * 8;
      float a0 = 0.0f, a1 = 0.0f;
#pragma unroll
      for (int k = 0; k < 8; ++k) {
        const float hd = S[b][384 + kb + k];
        a0 = fmaf(W2n[kb + k], hd, a0);
        a1 = fmaf(W2n[HDIM + kb + k], hd, a1);
      }
#pragma unroll
      for (int off = 8; off >= 1; off >>= 1) {
        a0 += __shfl_xor(a0, off, 16);
        a1 += __shfl_xor(a1, off, 16);
      }
      if (lane == 0) {
        const float l0 = a0 + b2n[0];
        const float l1 = a1 + b2n[1];
        const float m = fmaxf(l0, l1);
        const float e0 = expf(l0 - m);
        const float e1 = expf(l1 - m);
        const float sum = e0 + e1;
        const float p0 = e0 / sum + 1e-10f;
        const float p1 = e1 / sum + 1e-10f;
        const int gb = b0 + b;
        out[((size_t)gb * NSTEPS + n) * 2 + 0] = p0;
        out[((size_t)gb * NSTEPS + n) * 2 + 1] = p1;

        uint32_t k0n, k1n;
        tf2x32(0u, 42u, 0u, (uint32_t)n, k0n, k1n);  // fold-like split of key(42)
        uint32_t o0, o1;
        tf2x32(k0n, k1n, 0u, (uint32_t)(2 * gb), o0, o1);
        const float u0 = u01_from_bits(o0 ^ o1);
        tf2x32(k0n, k1n, 0u, (uint32_t)(2 * gb + 1), o0, o1);
        const float u1 = u01_from_bits(o0 ^ o1);
        const float g0 = -logf(-logf(u0));
        const float g1 = -logf(-logf(u1));
        const float z0 = logf(p0) + g0;
        const float z1 = logf(p1) + g1;
        const int smp = (z1 > z0) ? 1 : 0;  // argmax, first index wins ties
        xin[b][0] = (smp == 0) ? 1.0f : 0.0f;
        xin[b][1] = (smp == 1) ? 1.0f : 0.0f;
      }
    }
    __syncthreads();
  }
}

extern "C" void kernel_launch(void* const* d_in, const int* in_sizes, int n_in,
                              void* d_out, int out_size, void* d_ws, size_t ws_size,
                              hipStream_t stream) {
  (void)in_sizes; (void)n_in; (void)out_size; (void)d_ws; (void)ws_size;
  const float* inputs = (const float*)d_in[0];
  const float* Wih0 = (const float*)d_in[1];
  const float* Whh0 = (const float*)d_in[2];
  const float* bih0 = (const float*)d_in[3];
  const float* bhh0 = (const float*)d_in[4];
  const float* Wih1 = (const float*)d_in[5];
  const float* Whh1 = (const float*)d_in[6];
  const float* bih1 = (const float*)d_in[7];
  const float* bhh1 = (const float*)d_in[8];
  const float* W1 = (const float*)d_in[9];
  const float* b1 = (const float*)d_in[10];
  const float* W2 = (const float*)d_in[11];
  const float* b2 = (const float*)d_in[12];
  float* out = (float*)d_out;

  const int nblocks = 8192 / BT;  // 512 blocks, 2 per CU
  hipLaunchKernelGGL(rnn_wavefn_kernel, dim3(nblocks), dim3(THREADS), 0, stream,
                     inputs, Wih0, Whh0, bih0, bhh0, Wih1, Whh1, bih1, bhh1,
                     W1, b1, W2, b2, out);
}